// Round 5
// baseline (3238.413 us; speedup 1.0000x reference)
//
#include <hip/hip_runtime.h>
#include <hip/hip_bf16.h>

#define T_STEPS 512
#define BATCH   1024
#define HD1     80
#define HD2     100

#define W1_DW   (HD1 / 2)              // 40 packed dwords per lstm1 row
#define W2_DW   ((HD1 + HD2) / 2)      // 90 packed dwords per lstm2 row
#define NR1     (4 * HD1)              // 320 rows
#define NR2     (4 * HD2)              // 400 rows

#define HALF_DW 45                     // split-K: 45 weight dwords per worker

typedef _Float16 half2_t __attribute__((ext_vector_type(2)));

union HU { unsigned int u; half2_t h; };
static __device__ __forceinline__ half2_t bch(unsigned int u) { HU x; x.u = u; return x.h; }
static __device__ __forceinline__ unsigned int bcu(half2_t h) { HU x; x.h = h; return x.u; }

static __device__ __forceinline__ float dot2(half2_t a, half2_t b, float c) {
    return __builtin_amdgcn_fdot2(a, b, c, false);
}

// broadcast lane l's dword to all lanes via v_readlane (VALU, no LDS pipe)
static __device__ __forceinline__ half2_t rlh(unsigned int v, int l) {
    return bch((unsigned int)__builtin_amdgcn_readlane((int)v, l));
}

static __device__ __forceinline__ unsigned int packh(float a, float b) {
    half2_t p; p.x = (_Float16)a; p.y = (_Float16)b; return bcu(p);
}

// ---------------------------------------------------------------------------
// Prep: pack weights to f16 dwords, transposed [dword][row] for coalescing.
// ---------------------------------------------------------------------------
__global__ __launch_bounds__(256)
void prep_kernel(const float* __restrict__ W_hh1,
                 const float* __restrict__ W_ih2,
                 const float* __restrict__ W_hh2,
                 unsigned int* __restrict__ w1t,
                 unsigned int* __restrict__ w2t)
{
    int i = blockIdx.x * 256 + threadIdx.x;
    if (i < W1_DW * NR1) {
        int d = i / NR1, j = i % NR1;
        w1t[i] = packh(W_hh1[j * HD1 + 2 * d], W_hh1[j * HD1 + 2 * d + 1]);
    } else if (i < W1_DW * NR1 + W2_DW * NR2) {
        int k = i - W1_DW * NR1;
        int d = k / NR2, j = k % NR2;
        unsigned int p;
        if (d < W1_DW)
            p = packh(W_ih2[j * HD1 + 2 * d], W_ih2[j * HD1 + 2 * d + 1]);
        else {
            int dd = d - W1_DW;
            p = packh(W_hh2[j * HD2 + 2 * dd], W_hh2[j * HD2 + 2 * dd + 1]);
        }
        w2t[k] = p;
    }
}

// ---------------------------------------------------------------------------
// Phase 1: LSTM layer 1, ONE batch per block (1024 blocks x 320 threads).
//
// R5 CHANGE: broadcast uint4 LDS reads replaced by wave-cooperative
// ds_read_b32 (lane l reads h-dword l) + v_readlane SGPR broadcast.
// A broadcast ds_read_b128 still moves 64x16B=1KB through the per-CU LDS
// return path (~8-12cy, m134); 10 of them per thread-step was the hidden
// bottleneck. Now: 1 b32 read + 40 readlane + 40 dot2 per wave-step.
// ---------------------------------------------------------------------------
__global__ __launch_bounds__(NR1, 4)
void lstm1_kernel(const float* __restrict__ x,
                  const float* __restrict__ W_ih1,
                  const unsigned int* __restrict__ w1t,
                  const float* __restrict__ b_ih1,
                  const float* __restrict__ b_hh1,
                  _Float16* __restrict__ h1relu)
{
    const int j = threadIdx.x;
    const int b = blockIdx.x;
    const int q = j / HD1;
    const int m = j % HD1;

    unsigned int w[W1_DW];
#pragma unroll
    for (int d = 0; d < W1_DW; d++) w[d] = w1t[d * NR1 + j];
    const float wih  = W_ih1[j];
    const float bias = b_ih1[j] + b_hh1[j];

    __shared__ unsigned int hpd[64];   // dwords 0..39 = h (80 f16); 40..63 pad
    __shared__ float gates[NR1];
    __shared__ float xs[T_STEPS];

    if (j < 64) hpd[j] = 0u;
    for (int idx = j; idx < T_STEPS; idx += NR1)
        xs[idx] = x[(size_t)b * T_STEPS + idx];
    float c = 0.f;
    __syncthreads();

    for (int t = 0; t < T_STEPS; t++) {
        unsigned int hv = hpd[j & 63];         // 1 wave-coop b32 read
        float accP = fmaf(wih, xs[t], bias);
        float accQ = 0.f, accR = 0.f, accS = 0.f;
#pragma unroll
        for (int d = 0; d < W1_DW; d += 4) {
            accP = dot2(bch(w[d + 0]), rlh(hv, d + 0), accP);
            accQ = dot2(bch(w[d + 1]), rlh(hv, d + 1), accQ);
            accR = dot2(bch(w[d + 2]), rlh(hv, d + 2), accR);
            accS = dot2(bch(w[d + 3]), rlh(hv, d + 3), accS);
        }
        float z = (accP + accR) + (accQ + accS);
        z = (q == 2) ? 2.f * z : z;
        float s = 1.f / (1.f + __expf(-z));
        gates[j] = (q == 2) ? (2.f * s - 1.f) : s;
        __syncthreads();                      // gates ready

        if (j < HD1) {
            float gi = gates[m];
            float gf = gates[HD1 + m];
            float gg = gates[2 * HD1 + m];
            float go = gates[3 * HD1 + m];
            c = fmaf(gf, c, gi * gg);
            float th = 2.f / (1.f + __expf(-2.f * c)) - 1.f;
            float h = go * th;
            float hn = __shfl_down(h, 1, 64);
            if ((m & 1) == 0) {
                hpd[m >> 1] = packh(h, hn);
                *(unsigned int*)(h1relu + ((size_t)t * BATCH + b) * HD1 + m) =
                    packh(fmaxf(h, 0.f), fmaxf(hn, 0.f));
            }
        }
        __syncthreads();                      // hpd(t+1) ready
    }
}

// ---------------------------------------------------------------------------
// Phase 2: LSTM layer 2 — 2-way split-K + readlane broadcast.
// 1024 blocks x 960 threads (15 waves), one batch per block.
//
// R5 RATIONALE: R4 falsified the occupancy theory (occ 24->47%, dur WORSE;
// VALUBusy 42%). Shared culprit across R0-R4: broadcast uint4 LDS reads.
// 13 waves x 12 ds_read_b128/step = ~156KB/step of LDS return traffic for
// 180B of distinct data (~1200-1900 cy/step on the per-CU LDS pipe) — the
// real bottleneck. Fix: per wave, ONE ds_read_b32 (lane l reads h-dword
// base+l), then 45x v_readlane broadcast + 45 dot2 (VALU pipe, per-SIMD).
// readlane needs wave-uniform 'base' -> pad each half to 448 rows (7 waves):
//   waves 0..6  = half 0 (h1 dw 0..39 + h2 dw 0..4, +bias), rows wv*64+lane
//   waves 7..13 = half 1 (h2 dw 5..49),            rows (wv-7)*64+lane
//   rows >=400 clamped (compute garbage, don't write part)
//   wave 14: threads 896..935 stage h1 with 1-step prefetch
// hp[128] dwords: [0..39] h1, [40..89] h2, rest pad. part[2][400] partials;
// combine (j<100): z=p0+p1, 4 gates, c-update, packed h2 write. 2 barriers.
// __launch_bounds__(960,2): 30 waves/CU -> 64-reg tier; pressure ~56.
// ---------------------------------------------------------------------------
__global__ __launch_bounds__(960, 2)
void lstm2_kernel(const _Float16* __restrict__ h1relu,
                  const unsigned int* __restrict__ w2t,
                  const float* __restrict__ b_ih2,
                  const float* __restrict__ b_hh2,
                  float* __restrict__ h2last)
{
    const int j    = threadIdx.x;
    const int b0   = blockIdx.x;               // one batch per block
    const int wv   = j >> 6;                   // wave id 0..14
    const int lane = j & 63;
    const int half = (wv >= 7) ? 1 : 0;
    const int rawRow = (wv - 7 * half) * 64 + lane;    // 0..447 (wv<14)
    const bool worker = (wv < 14) && (rawRow < NR2);
    const int row = worker ? rawRow : (NR2 - 1);

    unsigned int w[HALF_DW];
#pragma unroll
    for (int d = 0; d < HALF_DW; d++)
        w[d] = w2t[(half * HALF_DW + d) * NR2 + row];
    const float bias = (half == 0) ? (b_ih2[row] + b_hh2[row]) : 0.f;

    __shared__ unsigned int hp[128];   // [0..39] h1, [40..89] h2, [90..127] pad
    __shared__ float part[2][NR2];

    if (j >= W1_DW && j < 128) hp[j] = 0u;     // zero h2 region + pad
    float c0 = 0.f;

    // stagers: wave 14, threads 896..935 each own one h1 dword
    const int  sj = j - 896;
    const bool stager = (sj >= 0) && (sj < W1_DW);
    const int  sk = stager ? sj : 0;
    unsigned int pf = 0;
    if (stager)
        pf = *(const unsigned int*)(h1relu + (size_t)b0 * HD1 + 2 * sk);

    const int base = half * HALF_DW;           // 0 or 45, wave-uniform

    for (int t = 0; t < T_STEPS; t++) {
        if (stager)
            hp[sk] = pf;                       // stage h1(t)
        __syncthreads();                       // hp: h1(t) + h2(t) ready

        if (wv < 14) {
            unsigned int hv = hp[base + lane]; // 1 wave-coop b32 read
            float aP = bias, aQ = 0.f, aR = 0.f, aS = 0.f;
#pragma unroll
            for (int d = 0; d < 44; d += 4) {
                aP = dot2(bch(w[d + 0]), rlh(hv, d + 0), aP);
                aQ = dot2(bch(w[d + 1]), rlh(hv, d + 1), aQ);
                aR = dot2(bch(w[d + 2]), rlh(hv, d + 2), aR);
                aS = dot2(bch(w[d + 3]), rlh(hv, d + 3), aS);
            }
            aP = dot2(bch(w[44]), rlh(hv, 44), aP);
            float z = (aP + aR) + (aQ + aS);
            if (worker) part[half][row] = z;
        } else if (stager && t + 1 < T_STEPS) {
            // wave 14: prefetch next h1 (hidden under dot phase)
            pf = *(const unsigned int*)(h1relu +
                     ((size_t)(t + 1) * BATCH + b0) * HD1 + 2 * sk);
        }
        __syncthreads();                       // part ready

        if (j < HD2) {                         // combine: threads 0..99
            float zi = part[0][j]           + part[1][j];
            float zf = part[0][HD2 + j]     + part[1][HD2 + j];
            float zg = part[0][2 * HD2 + j] + part[1][2 * HD2 + j];
            float zo = part[0][3 * HD2 + j] + part[1][3 * HD2 + j];
            float gi = 1.f / (1.f + __expf(-zi));
            float gf = 1.f / (1.f + __expf(-zf));
            float gg = 2.f / (1.f + __expf(-2.f * zg)) - 1.f;   // tanh
            float go = 1.f / (1.f + __expf(-zo));
            c0 = fmaf(gf, c0, gi * gg);
            float th = 2.f / (1.f + __expf(-2.f * c0)) - 1.f;
            float h0 = go * th;
            float h0n = __shfl_down(h0, 1, 64);
            if ((j & 1) == 0)
                hp[W1_DW + (j >> 1)] = packh(h0, h0n);   // h2 dwords 40..89
            if (t == T_STEPS - 1)
                h2last[(size_t)b0 * HD2 + j] = fmaxf(h0, 0.f);
        }
        // loop-top stage + barrier A covers h2(t+1) visibility
    }
}

// ---------------------------------------------------------------------------
// Head: out[b] = W_l2 @ relu(W_l1 @ h2last[b] + b_l1) + b_l2
// ---------------------------------------------------------------------------
__global__ __launch_bounds__(64)
void head_kernel(const float* __restrict__ h2last,
                 const float* __restrict__ W_l1,
                 const float* __restrict__ b_l1,
                 const float* __restrict__ W_l2,
                 const float* __restrict__ b_l2,
                 float* __restrict__ out)
{
    int b = blockIdx.x * 64 + threadIdx.x;
    if (b >= BATCH) return;
    const float* h = h2last + (size_t)b * HD2;
    float o = b_l2[0];
#pragma unroll
    for (int u = 0; u < 10; u++) {
        float s = b_l1[u];
#pragma unroll
        for (int k = 0; k < HD2; k++) s = fmaf(W_l1[u * HD2 + k], h[k], s);
        o = fmaf(W_l2[u], fmaxf(s, 0.f), o);
    }
    out[b] = o;
}

extern "C" void kernel_launch(void* const* d_in, const int* in_sizes, int n_in,
                              void* d_out, int out_size, void* d_ws, size_t ws_size,
                              hipStream_t stream)
{
    const float* x     = (const float*)d_in[0];
    const float* W_ih1 = (const float*)d_in[1];
    const float* W_hh1 = (const float*)d_in[2];
    const float* b_ih1 = (const float*)d_in[3];
    const float* b_hh1 = (const float*)d_in[4];
    const float* W_ih2 = (const float*)d_in[5];
    const float* W_hh2 = (const float*)d_in[6];
    const float* b_ih2 = (const float*)d_in[7];
    const float* b_hh2 = (const float*)d_in[8];
    const float* W_l1  = (const float*)d_in[9];
    const float* b_l1  = (const float*)d_in[10];
    const float* W_l2  = (const float*)d_in[11];
    const float* b_l2  = (const float*)d_in[12];
    float* out = (float*)d_out;

    // ws layout: h1relu f16 [t][b][k] (84 MB) | h2last f32 | w1t | w2t
    char* p = (char*)d_ws;
    _Float16* h1relu = (_Float16*)p;           p += (size_t)T_STEPS * BATCH * HD1 * 2;
    float* h2last    = (float*)p;              p += (size_t)BATCH * HD2 * 4;
    unsigned int* w1t = (unsigned int*)p;      p += (size_t)W1_DW * NR1 * 4;
    unsigned int* w2t = (unsigned int*)p;

    int prep_n = W1_DW * NR1 + W2_DW * NR2;
    hipLaunchKernelGGL(prep_kernel, dim3((prep_n + 255) / 256), dim3(256), 0, stream,
                       W_hh1, W_ih2, W_hh2, w1t, w2t);
    hipLaunchKernelGGL(lstm1_kernel, dim3(BATCH), dim3(NR1), 0, stream,
                       x, W_ih1, w1t, b_ih1, b_hh1, h1relu);
    hipLaunchKernelGGL(lstm2_kernel, dim3(BATCH), dim3(960), 0, stream,
                       h1relu, w2t, b_ih2, b_hh2, h2last);
    hipLaunchKernelGGL(head_kernel, dim3(BATCH / 64), dim3(64), 0, stream,
                       h2last, W_l1, b_l1, W_l2, b_l2, out);
}

// Round 6
// 1466.826 us; speedup vs baseline: 2.2078x; 2.2078x over previous
//
#include <hip/hip_runtime.h>
#include <hip/hip_bf16.h>

#define T_STEPS 512
#define BATCH   1024
#define HD1     80
#define HD2     100

#define W1_DW   (HD1 / 2)              // 40 packed dwords per lstm1 row
#define NR1     (4 * HD1)              // 320 rows
#define NR2     (4 * HD2)              // 400 rows

// ---- lstm2 MFMA geometry ----
#define NB2     16                     // batches per block
#define KDIM    192                    // 80 h1 + 100 h2 + 12 zero-pad
#define NKT     6                      // k-tiles of 32
#define NRT     25                     // row-tiles of 16 (400 rows)
#define ZSTR    404                    // Z LDS stride (dwords); %4==0, %32==20 -> 2-way max
#define W2F_DW  (NRT * NKT * 64 * 4)   // 38400 dwords of packed A-fragments

typedef _Float16 half2_t __attribute__((ext_vector_type(2)));
typedef _Float16 f16x8   __attribute__((ext_vector_type(8)));
typedef float    f32x4   __attribute__((ext_vector_type(4)));

union HU { unsigned int u; half2_t h; };
static __device__ __forceinline__ half2_t bch(unsigned int u) { HU x; x.u = u; return x.h; }
static __device__ __forceinline__ unsigned int bcu(half2_t h) { HU x; x.h = h; return x.u; }

static __device__ __forceinline__ float dot2(half2_t a, half2_t b, float c) {
    return __builtin_amdgcn_fdot2(a, b, c, false);
}

static __device__ __forceinline__ unsigned int packh(float a, float b) {
    half2_t p; p.x = (_Float16)a; p.y = (_Float16)b; return bcu(p);
}

// ---------------------------------------------------------------------------
// Prep:
//  - w1t: lstm1 W_hh1 packed f16 dwords, transposed [dword][row] (unchanged).
//  - w2f: lstm2 weights packed as PERSISTENT MFMA A-fragments.
//    Logical W2row[r][k]: k<80 -> W_ih2[r][k]; 80<=k<180 -> W_hh2[r][k-80];
//    k>=180 -> 0 (zero-pad to KDIM=192).
//    Fragment convention (gauge: same k-map used for B in lstm2):
//      half index H = ((ti*6+kt)*64 + lane)*8 + s
//      holds W2row[ti*16 + (lane&15)][kt*32 + (lane>>4)*8 + s]
// ---------------------------------------------------------------------------
__global__ __launch_bounds__(256)
void prep_kernel(const float* __restrict__ W_hh1,
                 const float* __restrict__ W_ih2,
                 const float* __restrict__ W_hh2,
                 unsigned int* __restrict__ w1t,
                 unsigned int* __restrict__ w2f)
{
    int i = blockIdx.x * 256 + threadIdx.x;
    if (i < W1_DW * NR1) {
        int d = i / NR1, j = i % NR1;
        w1t[i] = packh(W_hh1[j * HD1 + 2 * d], W_hh1[j * HD1 + 2 * d + 1]);
    } else if (i < W1_DW * NR1 + W2F_DW) {
        int d = i - W1_DW * NR1;               // dword index into w2f
        int H = 2 * d;                         // half index (s even)
        int ti = H / 3072;                     // row-tile 0..24
        int kt = (H / 512) % NKT;              // k-tile 0..5
        int l  = (H / 8) % 64;                 // lane
        int s  = H % 8;                        // slot (even)
        int r  = ti * 16 + (l & 15);
        int k  = kt * 32 + (l >> 4) * 8 + s;
        float v0, v1;
        v0 = (k < HD1) ? W_ih2[r * HD1 + k]
           : (k < HD1 + HD2) ? W_hh2[r * HD2 + (k - HD1)] : 0.f;
        int k1 = k + 1;
        v1 = (k1 < HD1) ? W_ih2[r * HD1 + k1]
           : (k1 < HD1 + HD2) ? W_hh2[r * HD2 + (k1 - HD1)] : 0.f;
        w2f[d] = packh(v0, v1);
    }
}

// ---------------------------------------------------------------------------
// Phase 1: LSTM layer 1 (reverted to the proven R4 version — R5's readlane
// variant regressed; broadcast uint4 LDS reads were never the bottleneck).
// ---------------------------------------------------------------------------
__global__ __launch_bounds__(NR1, 4)
void lstm1_kernel(const float* __restrict__ x,
                  const float* __restrict__ W_ih1,
                  const unsigned int* __restrict__ w1t,
                  const float* __restrict__ b_ih1,
                  const float* __restrict__ b_hh1,
                  _Float16* __restrict__ h1relu)
{
    const int j = threadIdx.x;
    const int b = blockIdx.x;
    const int q = j / HD1;
    const int m = j % HD1;

    unsigned int w[W1_DW];
#pragma unroll
    for (int d = 0; d < W1_DW; d++) w[d] = w1t[d * NR1 + j];
    const float wih  = W_ih1[j];
    const float bias = b_ih1[j] + b_hh1[j];

    __shared__ uint4 hp[HD1 / 8];     // 10 entries, 8 f16 values each
    __shared__ float gates[NR1];
    __shared__ float xs[T_STEPS];

    if (j < HD1 / 8) hp[j] = make_uint4(0u, 0u, 0u, 0u);
    for (int idx = j; idx < T_STEPS; idx += NR1)
        xs[idx] = x[(size_t)b * T_STEPS + idx];
    float c = 0.f;
    __syncthreads();

    for (int t = 0; t < T_STEPS; t++) {
        float accP = fmaf(wih, xs[t], bias);
        float accQ = 0.f;
#pragma unroll
        for (int k4 = 0; k4 < HD1 / 8; k4++) {
            uint4 U = hp[k4];
            accP = dot2(bch(w[4 * k4 + 0]), bch(U.x), accP);
            accQ = dot2(bch(w[4 * k4 + 1]), bch(U.y), accQ);
            accP = dot2(bch(w[4 * k4 + 2]), bch(U.z), accP);
            accQ = dot2(bch(w[4 * k4 + 3]), bch(U.w), accQ);
        }
        float z = accP + accQ;
        z = (q == 2) ? 2.f * z : z;
        float s = 1.f / (1.f + __expf(-z));
        gates[j] = (q == 2) ? (2.f * s - 1.f) : s;
        __syncthreads();                      // gates ready

        if (j < HD1) {
            float gi = gates[m];
            float gf = gates[HD1 + m];
            float gg = gates[2 * HD1 + m];
            float go = gates[3 * HD1 + m];
            c = fmaf(gf, c, gi * gg);
            float th = 2.f / (1.f + __expf(-2.f * c)) - 1.f;
            float h = go * th;
            float hn = __shfl_down(h, 1, 64);
            if ((m & 1) == 0) {
                ((unsigned int*)hp)[m >> 1] = packh(h, hn);
                *(unsigned int*)(h1relu + ((size_t)t * BATCH + b) * HD1 + m) =
                    packh(fmaxf(h, 0.f), fmaxf(hn, 0.f));
            }
        }
        __syncthreads();                      // hp(t+1) ready
    }
}

// ---------------------------------------------------------------------------
// Phase 2: LSTM layer 2 — MFMA. 64 blocks x 512 threads, 16 batches/block.
//
// R6 RATIONALE: dur x VALUBusy is CONSTANT (~780us) across R0-R4 -> dot2 is
// half-rate (~4cy), busy floor ~700us for both layers -> instruction-class
// change required, not scheduling. Per step: Z[400x16] = W2[400x192]xH[192x16]
// via mfma_f32_16x16x32_f16. Weights persistent in VGPRs (A-frags, 96
// VGPR/wave, loaded once). H (h1||h2, zero-padded to 192) lives in LDS in
// B-frag layout [k>>3][batch][k&7]; gate phase rebuilds it each step.
// A/B k-ordering is gauge-free (same bijection used in prep A-pack and LDS
// B-pack); C/D layout is the m89-verified col=lane&15, row=(lane>>4)*4+reg.
// 8 waves x 4 row-tiles (25 real, 7 benign duplicates). 2 barriers/step.
// ---------------------------------------------------------------------------
__global__ __launch_bounds__(512)
void lstm2_kernel(const _Float16* __restrict__ h1relu,
                  const _Float16* __restrict__ w2f,
                  const float* __restrict__ b_ih2,
                  const float* __restrict__ b_hh2,
                  float* __restrict__ h2last)
{
    const int tid = threadIdx.x;
    const int l   = tid & 63;
    const int wv  = tid >> 6;              // 0..7
    const int b0  = blockIdx.x * NB2;

    __shared__ _Float16 Hbuf[2][NKT * 4 * NB2 * 8];  // [kt*4+g][batch][slot], 6144B each
    __shared__ float    Zs[NB2 * ZSTR];              // Z[batch][row]
    __shared__ float    bias[NR2];

    // persistent A-fragments: 4 row-tiles x 6 k-tiles (all indices static)
    f16x8 a[4][6];
#pragma unroll
    for (int i = 0; i < 4; i++) {
        int ti = wv * 3 + i;               // 0..24 (waves overlap by 1 tile: benign dup)
#pragma unroll
        for (int kt = 0; kt < NKT; kt++)
            a[i][kt] = *(const f16x8*)(w2f + ((size_t)(ti * NKT + kt) * 64 + l) * 8);
    }

    // zero both H buffers (incl. k=180..191 pad), load bias
    for (int i = tid; i < 3072; i += 512) ((unsigned int*)Hbuf)[i] = 0u;
    for (int i = tid; i < NR2; i += 512) bias[i] = b_ih2[i] + b_hh2[i];
    __syncthreads();                       // zeros done before staging writes

    // stage h1(0) into Hbuf[0]; preload pfu = h1(1)
    const int sb = tid / 40;               // batch 0..15  (tid < 640)
    const int sk = tid % 40;               // h1 dword 0..39
    unsigned int pfu = 0;
    if (tid < 640) {
        unsigned int g0 = *(const unsigned int*)(h1relu + ((size_t)b0 + sb) * HD1 + 2 * sk);
        int k = 2 * sk;
        *(unsigned int*)&Hbuf[0][(k >> 3) * 128 + sb * 8 + (k & 7)] = g0;
        pfu = *(const unsigned int*)(h1relu + ((size_t)BATCH + b0 + sb) * HD1 + 2 * sk);
    }
    float c[4] = {0.f, 0.f, 0.f, 0.f};
    __syncthreads();

    int cur = 0;
    for (int t = 0; t < T_STEPS; t++) {
        // ---- MFMA phase: read B-frags, 24 MFMA, write Z ----
        f16x8 bfr[NKT];
#pragma unroll
        for (int kt = 0; kt < NKT; kt++)
            bfr[kt] = *(const f16x8*)&Hbuf[cur][(kt * 4 + (l >> 4)) * 128 + (l & 15) * 8];
#pragma unroll
        for (int i = 0; i < 4; i++) {
            f32x4 acc = {0.f, 0.f, 0.f, 0.f};
#pragma unroll
            for (int kt = 0; kt < NKT; kt++)
                acc = __builtin_amdgcn_mfma_f32_16x16x32_f16(a[i][kt], bfr[kt], acc, 0, 0, 0);
            int ti = wv * 3 + i;
            // C/D: col=lane&15 (batch), row=(lane>>4)*4+reg (verified m89)
            *(f32x4*)&Zs[(l & 15) * ZSTR + ti * 16 + ((l >> 4) << 2)] = acc;
        }
        __syncthreads();                   // Z ready

        // ---- gate phase: 1600 (unit,batch) pairs on 512 threads ----
#pragma unroll
        for (int kk = 0; kk < 4; kk++) {
            int P = tid + kk * 512;
            if (P < NB2 * HD2) {
                int unit = P % HD2, bt = P / HD2;
                float zi = Zs[bt * ZSTR + unit]            + bias[unit];
                float zf = Zs[bt * ZSTR + HD2 + unit]      + bias[HD2 + unit];
                float zg = Zs[bt * ZSTR + 2 * HD2 + unit]  + bias[2 * HD2 + unit];
                float zo = Zs[bt * ZSTR + 3 * HD2 + unit]  + bias[3 * HD2 + unit];
                float gi = 1.f / (1.f + __expf(-zi));
                float gf = 1.f / (1.f + __expf(-zf));
                float gg = 2.f / (1.f + __expf(-2.f * zg)) - 1.f;   // tanh
                float go = 1.f / (1.f + __expf(-zo));
                c[kk] = fmaf(gf, c[kk], gi * gg);
                float th = 2.f / (1.f + __expf(-2.f * c[kk])) - 1.f;
                float h = go * th;
                int k = HD1 + unit;        // h2 occupies k = 80..179
                Hbuf[cur ^ 1][(k >> 3) * 128 + bt * 8 + (k & 7)] = (_Float16)h;
                if (t == T_STEPS - 1)
                    h2last[(size_t)(b0 + bt) * HD2 + unit] = fmaxf(h, 0.f);
            }
        }
        // ---- h1 stage for step t+1 (prefetched last iteration) ----
        if (tid < 640) {
            int k = 2 * sk;
            *(unsigned int*)&Hbuf[cur ^ 1][(k >> 3) * 128 + sb * 8 + (k & 7)] = pfu;
            if (t + 2 < T_STEPS)
                pfu = *(const unsigned int*)(h1relu +
                         ((size_t)(t + 2) * BATCH + b0 + sb) * HD1 + 2 * sk);
        }
        __syncthreads();                   // Hbuf[nxt] complete
        cur ^= 1;
    }
}

// ---------------------------------------------------------------------------
// Head: out[b] = W_l2 @ relu(W_l1 @ h2last[b] + b_l1) + b_l2
// ---------------------------------------------------------------------------
__global__ __launch_bounds__(64)
void head_kernel(const float* __restrict__ h2last,
                 const float* __restrict__ W_l1,
                 const float* __restrict__ b_l1,
                 const float* __restrict__ W_l2,
                 const float* __restrict__ b_l2,
                 float* __restrict__ out)
{
    int b = blockIdx.x * 64 + threadIdx.x;
    if (b >= BATCH) return;
    const float* h = h2last + (size_t)b * HD2;
    float o = b_l2[0];
#pragma unroll
    for (int u = 0; u < 10; u++) {
        float s = b_l1[u];
#pragma unroll
        for (int k = 0; k < HD2; k++) s = fmaf(W_l1[u * HD2 + k], h[k], s);
        o = fmaf(W_l2[u], fmaxf(s, 0.f), o);
    }
    out[b] = o;
}

extern "C" void kernel_launch(void* const* d_in, const int* in_sizes, int n_in,
                              void* d_out, int out_size, void* d_ws, size_t ws_size,
                              hipStream_t stream)
{
    const float* x     = (const float*)d_in[0];
    const float* W_ih1 = (const float*)d_in[1];
    const float* W_hh1 = (const float*)d_in[2];
    const float* b_ih1 = (const float*)d_in[3];
    const float* b_hh1 = (const float*)d_in[4];
    const float* W_ih2 = (const float*)d_in[5];
    const float* W_hh2 = (const float*)d_in[6];
    const float* b_ih2 = (const float*)d_in[7];
    const float* b_hh2 = (const float*)d_in[8];
    const float* W_l1  = (const float*)d_in[9];
    const float* b_l1  = (const float*)d_in[10];
    const float* W_l2  = (const float*)d_in[11];
    const float* b_l2  = (const float*)d_in[12];
    float* out = (float*)d_out;

    // ws layout: h1relu f16 [t][b][k] (84 MB) | h2last f32 | w1t | w2f
    char* p = (char*)d_ws;
    _Float16* h1relu = (_Float16*)p;           p += (size_t)T_STEPS * BATCH * HD1 * 2;
    float* h2last    = (float*)p;              p += (size_t)BATCH * HD2 * 4;
    unsigned int* w1t = (unsigned int*)p;      p += (size_t)W1_DW * NR1 * 4;
    unsigned int* w2fu = (unsigned int*)p;     // 38400 dwords of A-fragments

    int prep_n = W1_DW * NR1 + W2F_DW;
    hipLaunchKernelGGL(prep_kernel, dim3((prep_n + 255) / 256), dim3(256), 0, stream,
                       W_hh1, W_ih2, W_hh2, w1t, w2fu);
    hipLaunchKernelGGL(lstm1_kernel, dim3(BATCH), dim3(NR1), 0, stream,
                       x, W_ih1, w1t, b_ih1, b_hh1, h1relu);
    hipLaunchKernelGGL(lstm2_kernel, dim3(BATCH / NB2), dim3(512), 0, stream,
                       h1relu, (const _Float16*)w2fu, b_ih2, b_hh2, h2last);
    hipLaunchKernelGGL(head_kernel, dim3(BATCH / 64), dim3(64), 0, stream,
                       h2last, W_l1, b_l1, W_l2, b_l2, out);
}

// Round 7
// 1393.837 us; speedup vs baseline: 2.3234x; 1.0524x over previous
//
#include <hip/hip_runtime.h>
#include <hip/hip_bf16.h>

#define T_STEPS 512
#define BATCH   1024
#define HD1     80
#define HD2     100

#define W1_DW   (HD1 / 2)              // 40 packed dwords per lstm1 row
#define NR1     (4 * HD1)              // 320 rows
#define NR2     (4 * HD2)              // 400 rows

// ---- lstm2 MFMA geometry (R7: gate-fused, 1 barrier/step) ----
#define NB2     16                     // batches per block (MFMA N=16)
#define NKT     6                      // k-tiles of 32 (K = 192 = 80 h1 + 100 h2 + 12 pad)
#define NUT     7                      // unit-tiles per gate (112 padded units)
#define NTILES  (4 * NUT)              // 28 row-tiles of 16
#define W2F_DW  (NTILES * NKT * 64 * 4) // 43008 dwords of packed A-fragments
#define HB_HALF (24 * NB2 * 8)         // 3072 halfs per H buffer

typedef _Float16 half2_t __attribute__((ext_vector_type(2)));
typedef _Float16 f16x4   __attribute__((ext_vector_type(4)));
typedef _Float16 f16x8   __attribute__((ext_vector_type(8)));
typedef float    f32x4   __attribute__((ext_vector_type(4)));

union HU { unsigned int u; half2_t h; };
static __device__ __forceinline__ half2_t bch(unsigned int u) { HU x; x.u = u; return x.h; }
static __device__ __forceinline__ unsigned int bcu(half2_t h) { HU x; x.h = h; return x.u; }

static __device__ __forceinline__ float dot2(half2_t a, half2_t b, float c) {
    return __builtin_amdgcn_fdot2(a, b, c, false);
}

static __device__ __forceinline__ unsigned int packh(float a, float b) {
    half2_t p; p.x = (_Float16)a; p.y = (_Float16)b; return bcu(p);
}

// ---------------------------------------------------------------------------
// Prep:
//  - w1t: lstm1 W_hh1 packed f16 dwords, transposed [dword][row] (unchanged).
//  - w2f: lstm2 weights as persistent MFMA A-fragments, GATE-PADDED rows:
//    each gate padded 100 -> 112 units; tile id = g*7 + j (j = unit-tile).
//    Fragment gauge (same k-map as the lstm2 B-pack; R6-verified):
//      half F = ((tile*6 + kt)*64 + lane)*8 + s holds
//      W2pad[g][u' = j*16 + (lane&15)][k = kt*32 + (lane>>4)*8 + s]
//    W2pad: u'>=100 -> 0; k<80 -> W_ih2[r][k]; k<180 -> W_hh2[r][k-80]; else 0
//    (r = g*100 + u').
// ---------------------------------------------------------------------------
__global__ __launch_bounds__(256)
void prep_kernel(const float* __restrict__ W_hh1,
                 const float* __restrict__ W_ih2,
                 const float* __restrict__ W_hh2,
                 unsigned int* __restrict__ w1t,
                 unsigned int* __restrict__ w2f)
{
    int i = blockIdx.x * 256 + threadIdx.x;
    if (i < W1_DW * NR1) {
        int d = i / NR1, j = i % NR1;
        w1t[i] = packh(W_hh1[j * HD1 + 2 * d], W_hh1[j * HD1 + 2 * d + 1]);
    } else if (i < W1_DW * NR1 + W2F_DW) {
        int d  = i - W1_DW * NR1;              // dword index into w2f
        int H  = 2 * d;                        // half index (s even)
        int s  = H % 8;
        int l  = (H / 8) % 64;
        int kt = (H / 512) % NKT;
        int tile = H / 3072;                   // 0..27
        int g  = tile / NUT;
        int j  = tile % NUT;
        int up = j * 16 + (l & 15);            // padded unit 0..111
        int k  = kt * 32 + (l >> 4) * 8 + s;
        float v0 = 0.f, v1 = 0.f;
        if (up < HD2) {
            int r = g * HD2 + up;
            v0 = (k < HD1) ? W_ih2[r * HD1 + k]
               : (k < HD1 + HD2) ? W_hh2[r * HD2 + (k - HD1)] : 0.f;
            int k1 = k + 1;
            v1 = (k1 < HD1) ? W_ih2[r * HD1 + k1]
               : (k1 < HD1 + HD2) ? W_hh2[r * HD2 + (k1 - HD1)] : 0.f;
        }
        w2f[d] = packh(v0, v1);
    }
}

// ---------------------------------------------------------------------------
// Phase 1: LSTM layer 1 (unchanged — proven R4 version).
// ---------------------------------------------------------------------------
__global__ __launch_bounds__(NR1, 4)
void lstm1_kernel(const float* __restrict__ x,
                  const float* __restrict__ W_ih1,
                  const unsigned int* __restrict__ w1t,
                  const float* __restrict__ b_ih1,
                  const float* __restrict__ b_hh1,
                  _Float16* __restrict__ h1relu)
{
    const int j = threadIdx.x;
    const int b = blockIdx.x;
    const int q = j / HD1;
    const int m = j % HD1;

    unsigned int w[W1_DW];
#pragma unroll
    for (int d = 0; d < W1_DW; d++) w[d] = w1t[d * NR1 + j];
    const float wih  = W_ih1[j];
    const float bias = b_ih1[j] + b_hh1[j];

    __shared__ uint4 hp[HD1 / 8];
    __shared__ float gates[NR1];
    __shared__ float xs[T_STEPS];

    if (j < HD1 / 8) hp[j] = make_uint4(0u, 0u, 0u, 0u);
    for (int idx = j; idx < T_STEPS; idx += NR1)
        xs[idx] = x[(size_t)b * T_STEPS + idx];
    float c = 0.f;
    __syncthreads();

    for (int t = 0; t < T_STEPS; t++) {
        float accP = fmaf(wih, xs[t], bias);
        float accQ = 0.f;
#pragma unroll
        for (int k4 = 0; k4 < HD1 / 8; k4++) {
            uint4 U = hp[k4];
            accP = dot2(bch(w[4 * k4 + 0]), bch(U.x), accP);
            accQ = dot2(bch(w[4 * k4 + 1]), bch(U.y), accQ);
            accP = dot2(bch(w[4 * k4 + 2]), bch(U.z), accP);
            accQ = dot2(bch(w[4 * k4 + 3]), bch(U.w), accQ);
        }
        float z = accP + accQ;
        z = (q == 2) ? 2.f * z : z;
        float s = 1.f / (1.f + __expf(-z));
        gates[j] = (q == 2) ? (2.f * s - 1.f) : s;
        __syncthreads();

        if (j < HD1) {
            float gi = gates[m];
            float gf = gates[HD1 + m];
            float gg = gates[2 * HD1 + m];
            float go = gates[3 * HD1 + m];
            c = fmaf(gf, c, gi * gg);
            float th = 2.f / (1.f + __expf(-2.f * c)) - 1.f;
            float h = go * th;
            float hn = __shfl_down(h, 1, 64);
            if ((m & 1) == 0) {
                ((unsigned int*)hp)[m >> 1] = packh(h, hn);
                *(unsigned int*)(h1relu + ((size_t)t * BATCH + b) * HD1 + m) =
                    packh(fmaxf(h, 0.f), fmaxf(hn, 0.f));
            }
        }
        __syncthreads();
    }
}

// ---------------------------------------------------------------------------
// Phase 2: LSTM layer 2 — MFMA with IN-REGISTER GATES. 64 blocks x 512 thr.
//
// R7 RATIONALE: R6 counters (VALUBusy 14.7%, MfmaUtil 4.5%, occ 6%) show a
// latency race: 4270 cy/step vs ~600 cy of issue work. The Zs LDS round-trip
// + 4 serialized gate rounds (each 4x ~120cy dependent LDS loads + exp
// chains) were ~2500 cy of the path. Fix: pad gates to 112 units; wave w
// owns tiles {g*7+w, g=0..3} = ALL 4 gates of units w*16..w*16+15. With the
// verified C/D map (col=lane&15=batch, row=(lane>>4)*4+reg=unit-offset),
// i/f/g/o of unit u, batch b land in ONE lane -> gates+c+h entirely in
// registers. No Zs, no gate rounds, ONE barrier/step. Wave 7 stages h1
// (10 dwords/lane, 1-step reg prefetch — also fixes R6's staging hole where
// tid<640 on a 512-thread block left batches 13..15 unstaged).
// ---------------------------------------------------------------------------
__global__ __launch_bounds__(512, 1)
void lstm2_kernel(const _Float16* __restrict__ h1relu,
                  const _Float16* __restrict__ w2f,
                  const float* __restrict__ b_ih2,
                  const float* __restrict__ b_hh2,
                  float* __restrict__ h2last)
{
    const int tid = threadIdx.x;
    const int l   = tid & 63;
    const int wv  = tid >> 6;              // 0..7
    const int b0  = blockIdx.x * NB2;
    const int bt  = l & 15;                // batch column
    const int u0  = wv * 16 + ((l >> 4) << 2);   // first unit of this lane
    const bool workerWave = (wv < 7);
    const bool worker = workerWave && (u0 < HD2);   // whole 4-unit group valid

    __shared__ _Float16 Hbuf[2][HB_HALF];  // [k>>3][batch][k&7] f16, dbuf

    // persistent A-fragments: 4 gates x 6 k-tiles (statically indexed)
    const int wvc = workerWave ? wv : 6;
    f16x8 a[4][NKT];
#pragma unroll
    for (int g = 0; g < 4; g++)
#pragma unroll
        for (int kt = 0; kt < NKT; kt++)
            a[g][kt] = *(const f16x8*)(w2f +
                ((size_t)((g * NUT + wvc) * NKT + kt) * 64 + l) * 8);

    // per-lane bias: 4 gates x 4 units (clamped reads for invalid lanes)
    float bs[4][4];
#pragma unroll
    for (int g = 0; g < 4; g++)
#pragma unroll
        for (int r = 0; r < 4; r++) {
            int uu = (u0 + r < HD2) ? (u0 + r) : 0;
            bs[g][r] = b_ih2[g * HD2 + uu] + b_hh2[g * HD2 + uu];
        }

    float c[4] = {0.f, 0.f, 0.f, 0.f};

    // zero both H buffers (3072 dwords)
    for (int i = tid; i < HB_HALF; i += 512) ((unsigned int*)Hbuf)[i] = 0u;
    __syncthreads();

    // stager (wave 7): lane l owns pairs p = l + 64q, q=0..9 -> (sb,sk)
    unsigned int pf[10];
    if (wv == 7) {
#pragma unroll
        for (int q = 0; q < 10; q++) {
            int p = l + 64 * q;
            int sb = p / 40, sk = p % 40, k = 2 * sk;
            unsigned int g0 = *(const unsigned int*)
                (h1relu + ((size_t)b0 + sb) * HD1 + 2 * sk);
            *(unsigned int*)&Hbuf[0][(k >> 3) * 128 + sb * 8 + (k & 7)] = g0;
            pf[q] = *(const unsigned int*)
                (h1relu + ((size_t)BATCH + b0 + sb) * HD1 + 2 * sk);
        }
    }
    __syncthreads();

    int cur = 0;
    for (int t = 0; t < T_STEPS; t++) {
        if (workerWave) {
            // B-frags for this step (R6-verified layout/gauge)
            f16x8 bfr[NKT];
#pragma unroll
            for (int kt = 0; kt < NKT; kt++)
                bfr[kt] = *(const f16x8*)
                    &Hbuf[cur][(kt * 4 + (l >> 4)) * 128 + bt * 8];

            f32x4 acc[4];
#pragma unroll
            for (int g = 0; g < 4; g++) {
                f32x4 z4 = {0.f, 0.f, 0.f, 0.f};
#pragma unroll
                for (int kt = 0; kt < NKT; kt++)
                    z4 = __builtin_amdgcn_mfma_f32_16x16x32_f16(
                             a[g][kt], bfr[kt], z4, 0, 0, 0);
                acc[g] = z4;
            }

            if (worker) {                      // lane-divergent, no wave ops
                f16x4 hh;
#pragma unroll
                for (int r = 0; r < 4; r++) {
                    float zi = acc[0][r] + bs[0][r];
                    float zf = acc[1][r] + bs[1][r];
                    float zg = acc[2][r] + bs[2][r];
                    float zo = acc[3][r] + bs[3][r];
                    float gi = 1.f / (1.f + __expf(-zi));
                    float gf = 1.f / (1.f + __expf(-zf));
                    float gg = 2.f / (1.f + __expf(-2.f * zg)) - 1.f; // tanh
                    float go = 1.f / (1.f + __expf(-zo));
                    c[r] = fmaf(gf, c[r], gi * gg);
                    float th = 2.f / (1.f + __expf(-2.f * c[r])) - 1.f;
                    float h = go * th;
                    hh[r] = (_Float16)h;
                    if (t == T_STEPS - 1)
                        h2last[(size_t)(b0 + bt) * HD2 + u0 + r] = fmaxf(h, 0.f);
                }
                int k0 = HD1 + u0;             // k = 80..179, k0&7 in {0,4}
                *(f16x4*)&Hbuf[cur ^ 1][(k0 >> 3) * 128 + bt * 8 + (k0 & 7)] = hh;
            }
        } else {
            // stager: write h1(t+1), prefetch h1(t+2)
            if (t + 1 < T_STEPS) {
#pragma unroll
                for (int q = 0; q < 10; q++) {
                    int p = l + 64 * q;
                    int sb = p / 40, sk = p % 40, k = 2 * sk;
                    *(unsigned int*)&Hbuf[cur ^ 1]
                        [(k >> 3) * 128 + sb * 8 + (k & 7)] = pf[q];
                    if (t + 2 < T_STEPS)
                        pf[q] = *(const unsigned int*)(h1relu +
                            ((size_t)(t + 2) * BATCH + b0 + sb) * HD1 + 2 * sk);
                }
            }
        }
        __syncthreads();                       // single barrier per step
        cur ^= 1;
    }
}

// ---------------------------------------------------------------------------
// Head: out[b] = W_l2 @ relu(W_l1 @ h2last[b] + b_l1) + b_l2
// ---------------------------------------------------------------------------
__global__ __launch_bounds__(64)
void head_kernel(const float* __restrict__ h2last,
                 const float* __restrict__ W_l1,
                 const float* __restrict__ b_l1,
                 const float* __restrict__ W_l2,
                 const float* __restrict__ b_l2,
                 float* __restrict__ out)
{
    int b = blockIdx.x * 64 + threadIdx.x;
    if (b >= BATCH) return;
    const float* h = h2last + (size_t)b * HD2;
    float o = b_l2[0];
#pragma unroll
    for (int u = 0; u < 10; u++) {
        float s = b_l1[u];
#pragma unroll
        for (int k = 0; k < HD2; k++) s = fmaf(W_l1[u * HD2 + k], h[k], s);
        o = fmaf(W_l2[u], fmaxf(s, 0.f), o);
    }
    out[b] = o;
}

extern "C" void kernel_launch(void* const* d_in, const int* in_sizes, int n_in,
                              void* d_out, int out_size, void* d_ws, size_t ws_size,
                              hipStream_t stream)
{
    const float* x     = (const float*)d_in[0];
    const float* W_ih1 = (const float*)d_in[1];
    const float* W_hh1 = (const float*)d_in[2];
    const float* b_ih1 = (const float*)d_in[3];
    const float* b_hh1 = (const float*)d_in[4];
    const float* W_ih2 = (const float*)d_in[5];
    const float* W_hh2 = (const float*)d_in[6];
    const float* b_ih2 = (const float*)d_in[7];
    const float* b_hh2 = (const float*)d_in[8];
    const float* W_l1  = (const float*)d_in[9];
    const float* b_l1  = (const float*)d_in[10];
    const float* W_l2  = (const float*)d_in[11];
    const float* b_l2  = (const float*)d_in[12];
    float* out = (float*)d_out;

    // ws layout: h1relu f16 [t][b][k] (84 MB) | h2last f32 | w1t | w2f
    char* p = (char*)d_ws;
    _Float16* h1relu = (_Float16*)p;           p += (size_t)T_STEPS * BATCH * HD1 * 2;
    float* h2last    = (float*)p;              p += (size_t)BATCH * HD2 * 4;
    unsigned int* w1t = (unsigned int*)p;      p += (size_t)W1_DW * NR1 * 4;
    unsigned int* w2fu = (unsigned int*)p;     // 43008 dwords of A-fragments

    int prep_n = W1_DW * NR1 + W2F_DW;
    hipLaunchKernelGGL(prep_kernel, dim3((prep_n + 255) / 256), dim3(256), 0, stream,
                       W_hh1, W_ih2, W_hh2, w1t, w2fu);
    hipLaunchKernelGGL(lstm1_kernel, dim3(BATCH), dim3(NR1), 0, stream,
                       x, W_ih1, w1t, b_ih1, b_hh1, h1relu);
    hipLaunchKernelGGL(lstm2_kernel, dim3(BATCH / NB2), dim3(512), 0, stream,
                       h1relu, (const _Float16*)w2fu, b_ih2, b_hh2, h2last);
    hipLaunchKernelGGL(head_kernel, dim3(BATCH / 64), dim3(64), 0, stream,
                       h2last, W_l1, b_l1, W_l2, b_l2, out);
}